// Round 5
// baseline (247.905 us; speedup 1.0000x reference)
//
#include <hip/hip_runtime.h>
#include <hip/hip_bf16.h>

// ---------------------------------------------------------------------------
// DeformableSpatialEncoder on MI355X (gfx950)
//
// R4 insight: feat is consumed ONLY by the value/off/aw linears, so
//   catout = (A@Wemb^T + eb)@Wcat^T + bcat = A@Wfused^T + bfused,
//   Wfused = Wcat@Wemb  [896,768]  (1.06 GF, tiny GEMM)
//   bfused = Wcat@embed_b + bcat   [896]    (merged into stage)
// -> the 14.8 GF gemm1 is eliminated; one 17.3 GF GEMM remains.
//
// Pipeline (N=64 images, Lq=196, D=768, heads=4, Dh=192, points=4):
//   1. stage:  im2col x->A bf16 [12544,768] + Wcat bf16 + WembT bf16
//              (transposed cast) + bfused dots + zeros
//   2. wfuse:  Wfused bf16 [896,768] = Wcat @ Wemb   (gemm_bt, 42 blocks)
//   3. main:   value->Vbuf bf16 [12544,768], off/aw->OA f32 [12544,64]
//              = A @ Wfused^T + bfused  (mixed epilogue)
//   4. deform: core_mean[64,768] += mean_lq( softmax(aw)*bilinear(value) )
//   5. pooled = core_mean @ outp_w^T + outp_b   (mean commutes with linear)
//   6. final  = pooled @ proj_w^T + proj_b -> d_out
// ---------------------------------------------------------------------------

using bf16 = __bf16;
typedef bf16  bf16x8 __attribute__((ext_vector_type(8)));
typedef float f32x4  __attribute__((ext_vector_type(4)));

#define N_IMG   64
#define LQ      196
#define DM      768
#define NH      4
#define DH      192
#define M_ROWS  (N_IMG * LQ)        // 12544
#define NCAT    896                 // 768 value + 32 off + 16 aw + 80 pad

// ---- workspace layout (bytes, all 256-aligned) ----
#define OFF_A      ((size_t)0)                     // 12544*768*2 = 19267584
#define OFF_WEMBT  (OFF_A     + 19267584)          // 768*768*2   = 1179648
#define OFF_WCAT   (OFF_WEMBT + 1179648)           // 896*768*2   = 1376256
#define OFF_WFUSE  (OFF_WCAT  + 1376256)           // 896*768*2   = 1376256
#define OFF_BFUSE  (OFF_WFUSE + 1376256)           // 4096
#define OFF_ZB     (OFF_BFUSE + 4096)              // 4096 (zero bias)
#define OFF_VBUF   (OFF_ZB    + 4096)              // 12544*768*2 = 19267584
#define OFF_OA     (OFF_VBUF  + 19267584)          // 12544*64*4  = 3211264
#define OFF_CORE   (OFF_OA    + 3211264)           // 196608
#define OFF_POOL   (OFF_CORE  + 196608)            // 196608

__device__ __forceinline__ void gload_lds16(const bf16* g, bf16* l) {
#if __has_builtin(__builtin_amdgcn_global_load_lds)
  __builtin_amdgcn_global_load_lds(
      (const __attribute__((address_space(1))) void*)g,
      (__attribute__((address_space(3))) void*)l, 16, 0, 0);
#else
  *(bf16x8*)l = *(const bf16x8*)g;
#endif
}

// ---------------------------------------------------------------------------
// stage: blocks [0,9408)          im2col (coalesced both sides)
//        blocks [9408,12096)      prep: Wcat cast, WembT transposed cast,
//                                 core zero, zero-bias init
//        blocks [12096,12124)     bfused: 8 threads per output dot
// ---------------------------------------------------------------------------
__global__ void stage_kernel(const float* __restrict__ x,
                             const float* __restrict__ embed_w,
                             const float* __restrict__ embed_b,
                             const float* __restrict__ value_w,
                             const float* __restrict__ off_w,
                             const float* __restrict__ aw_w,
                             const float* __restrict__ value_b,
                             const float* __restrict__ off_b,
                             const float* __restrict__ aw_b,
                             bf16* __restrict__ A,
                             bf16* __restrict__ WembT, bf16* __restrict__ Wcat,
                             float* __restrict__ bfused, float* __restrict__ zb,
                             float* __restrict__ core) {
  const int bid = blockIdx.x;
  if (bid < 9408) {                       // ---- im2col ----
    const int t   = bid * 256 + threadIdx.x;   // < 12544*192 exactly
    const int row = t / 192;
    const int j   = t - row * 192;
    const int k   = j * 4;                // k = c*256 + p*16 + q, q%4==0
    const int c   = k >> 8;
    const int r   = k & 255;
    const int p   = r >> 4;
    const int q   = r & 15;
    const int n   = row / 196;
    const int lq  = row - n * 196;
    const int h   = lq / 14;
    const int w   = lq - h * 14;
    const float4 v = *(const float4*)(x +
        ((((size_t)n * 3 + c) * 224) + h * 16 + p) * 224 + w * 16 + q);
    bf16* dst = A + (size_t)row * DM + k;
    dst[0] = (bf16)v.x; dst[1] = (bf16)v.y; dst[2] = (bf16)v.z; dst[3] = (bf16)v.w;
    return;
  }
  if (bid < 12096) {                      // ---- prep ----
    const int idx = (bid - 9408) * 256 + threadIdx.x;   // < 688128 = 896*768
    {
      int rr = idx / DM, kk = idx - rr * DM;
      float v = 0.f;
      if (rr < 768)       v = value_w[idx];
      else if (rr < 800)  v = off_w[(rr - 768) * DM + kk];
      else if (rr < 816)  v = aw_w[(rr - 800) * DM + kk];
      Wcat[idx] = (bf16)v;
    }
    if (idx < DM * DM) {
      // WembT[k][j] = embed_w[j][k]
      int kk = idx / DM, jj = idx - kk * DM;
      WembT[idx] = (bf16)embed_w[(size_t)jj * DM + kk];
    }
    if (idx < DM) zb[idx] = 0.f;
    if (idx < N_IMG * DM) core[idx] = 0.f;
    return;
  }
  // ---- bfused: r = 32 per block, 8 threads per dot ----
  const int t  = threadIdx.x;
  const int r  = (bid - 12096) * 32 + (t >> 3);   // 0..895
  const int t8 = t & 7;
  const float* src = nullptr;
  float badd = 0.f;
  if (r < 768)      { src = value_w + (size_t)r * DM;        badd = value_b[r]; }
  else if (r < 800) { src = off_w  + (size_t)(r - 768) * DM; badd = off_b[r - 768]; }
  else if (r < 816) { src = aw_w   + (size_t)(r - 800) * DM; badd = aw_b[r - 800]; }
  float s = 0.f;
  if (src) {
    for (int j = t8; j < DM; j += 8) s += src[j] * embed_b[j];
  }
#pragma unroll
  for (int o = 4; o >= 1; o >>= 1) s += __shfl_down(s, o, 8);
  if (t8 == 0) bfused[r] = (src ? s + badd : 0.f);
}

// ---------------------------------------------------------------------------
// gemm_bt: C[M,N] = A[M,K]bf16 @ B[N,K]bf16 ^T + bias[N]
// 128x128 tile, BK=64, 256 threads (4 waves, 2x2), mfma_f32_16x16x32_bf16.
// grid = (N/128, M/128), N-tile fast.
// ---------------------------------------------------------------------------
template <typename OutT>
__global__ void gemm_bt(const bf16* __restrict__ A, const bf16* __restrict__ B,
                        const float* __restrict__ bias, OutT* __restrict__ C,
                        int M, int N, int K) {
  __shared__ bf16 As[128 * 64];
  __shared__ bf16 Bs[128 * 64];

  const int tid  = threadIdx.x;
  const int wave = tid >> 6;
  const int lane = tid & 63;
  const int nBase = blockIdx.x * 128;
  const int mBase = blockIdx.y * 128;
  const int wm = wave & 1;
  const int wn = wave >> 1;
  const int quad = lane >> 4;
  const int r16  = lane & 15;

  const f32x4 zero = {0.f, 0.f, 0.f, 0.f};
  f32x4 acc[4][4];
#pragma unroll
  for (int mi = 0; mi < 4; ++mi)
#pragma unroll
    for (int ni = 0; ni < 4; ++ni) acc[mi][ni] = zero;

  const int srow = wave * 32 + (lane >> 3);
  const int scol = (lane & 7) * 8;
  const bf16* Ag = A + (size_t)(mBase + srow) * K + scol;
  const bf16* Bg = B + (size_t)(nBase + srow) * K + scol;
  bf16* Al = As + srow * 64 + scol;
  bf16* Bl = Bs + srow * 64 + scol;

  for (int kt = 0; kt < K; kt += 64) {
#pragma unroll
    for (int i = 0; i < 4; ++i) {
      gload_lds16(Ag + (size_t)(i * 8) * K + kt, Al + i * 8 * 64);
      gload_lds16(Bg + (size_t)(i * 8) * K + kt, Bl + i * 8 * 64);
    }
    __syncthreads();
#pragma unroll
    for (int kk = 0; kk < 64; kk += 32) {
      bf16x8 af[4], bfr[4];
#pragma unroll
      for (int mi = 0; mi < 4; ++mi)
        af[mi] = *(const bf16x8*)&As[(wm * 64 + mi * 16 + r16) * 64 + kk + quad * 8];
#pragma unroll
      for (int ni = 0; ni < 4; ++ni)
        bfr[ni] = *(const bf16x8*)&Bs[(wn * 64 + ni * 16 + r16) * 64 + kk + quad * 8];
#pragma unroll
      for (int mi = 0; mi < 4; ++mi)
#pragma unroll
        for (int ni = 0; ni < 4; ++ni)
          acc[mi][ni] = __builtin_amdgcn_mfma_f32_16x16x32_bf16(
              af[mi], bfr[ni], acc[mi][ni], 0, 0, 0);
    }
    __syncthreads();
  }

  // epilogue: C row = quad*4 + reg, col = lane&15 (m89/m91-verified layout)
#pragma unroll
  for (int ni = 0; ni < 4; ++ni) {
    const int col = nBase + wn * 64 + ni * 16 + r16;
    const float bv = bias[col];
#pragma unroll
    for (int mi = 0; mi < 4; ++mi) {
      const int row0 = mBase + wm * 64 + mi * 16 + quad * 4;
#pragma unroll
      for (int rr = 0; rr < 4; ++rr) {
        float v = acc[mi][ni][rr] + bv;
        C[(size_t)(row0 + rr) * N + col] = (OutT)v;
      }
    }
  }
}

// ---------------------------------------------------------------------------
// gemm2_mixed: same K-loop; epilogue splits columns:
//   col <  768 -> Vbuf bf16 [M,768]
//   col <  816 -> OA   f32  [M,64]  at col-768 (0..31 off, 32..47 aw)
//   col >= 816 -> dropped (zero-pad columns)
// ---------------------------------------------------------------------------
__global__ void gemm2_mixed(const bf16* __restrict__ A, const bf16* __restrict__ B,
                            const float* __restrict__ bias,
                            bf16* __restrict__ Vb, float* __restrict__ OA,
                            int M, int N, int K) {
  __shared__ bf16 As[128 * 64];
  __shared__ bf16 Bs[128 * 64];

  const int tid  = threadIdx.x;
  const int wave = tid >> 6;
  const int lane = tid & 63;
  const int nBase = blockIdx.x * 128;
  const int mBase = blockIdx.y * 128;
  const int wm = wave & 1;
  const int wn = wave >> 1;
  const int quad = lane >> 4;
  const int r16  = lane & 15;

  const f32x4 zero = {0.f, 0.f, 0.f, 0.f};
  f32x4 acc[4][4];
#pragma unroll
  for (int mi = 0; mi < 4; ++mi)
#pragma unroll
    for (int ni = 0; ni < 4; ++ni) acc[mi][ni] = zero;

  const int srow = wave * 32 + (lane >> 3);
  const int scol = (lane & 7) * 8;
  const bf16* Ag = A + (size_t)(mBase + srow) * K + scol;
  const bf16* Bg = B + (size_t)(nBase + srow) * K + scol;
  bf16* Al = As + srow * 64 + scol;
  bf16* Bl = Bs + srow * 64 + scol;

  for (int kt = 0; kt < K; kt += 64) {
#pragma unroll
    for (int i = 0; i < 4; ++i) {
      gload_lds16(Ag + (size_t)(i * 8) * K + kt, Al + i * 8 * 64);
      gload_lds16(Bg + (size_t)(i * 8) * K + kt, Bl + i * 8 * 64);
    }
    __syncthreads();
#pragma unroll
    for (int kk = 0; kk < 64; kk += 32) {
      bf16x8 af[4], bfr[4];
#pragma unroll
      for (int mi = 0; mi < 4; ++mi)
        af[mi] = *(const bf16x8*)&As[(wm * 64 + mi * 16 + r16) * 64 + kk + quad * 8];
#pragma unroll
      for (int ni = 0; ni < 4; ++ni)
        bfr[ni] = *(const bf16x8*)&Bs[(wn * 64 + ni * 16 + r16) * 64 + kk + quad * 8];
#pragma unroll
      for (int mi = 0; mi < 4; ++mi)
#pragma unroll
        for (int ni = 0; ni < 4; ++ni)
          acc[mi][ni] = __builtin_amdgcn_mfma_f32_16x16x32_bf16(
              af[mi], bfr[ni], acc[mi][ni], 0, 0, 0);
    }
    __syncthreads();
  }

#pragma unroll
  for (int ni = 0; ni < 4; ++ni) {
    const int col = nBase + wn * 64 + ni * 16 + r16;
    const float bv = bias[col];
#pragma unroll
    for (int mi = 0; mi < 4; ++mi) {
      const int row0 = mBase + wm * 64 + mi * 16 + quad * 4;
#pragma unroll
      for (int rr = 0; rr < 4; ++rr) {
        float v = acc[mi][ni][rr] + bv;
        int row = row0 + rr;
        if (col < 768) {
          Vb[(size_t)row * 768 + col] = (bf16)v;
        } else if (col < 816) {
          OA[(size_t)row * 64 + (col - 768)] = v;
        }
      }
    }
  }
}

// ---------------------------------------------------------------------------
// deform: grid (64, 49, 3), block 256.
// Phase 1 (64 threads): per (lq_i, head, point) combined weights + clamped
//   token indices -> LDS (reads off/aw from OA f32 [12544,64]).
// Phase 2 (256 threads): thread = channel; 64 unconditional bf16 gathers.
// ---------------------------------------------------------------------------
__global__ void deform_kernel(const bf16* __restrict__ Vb,
                              const float* __restrict__ OA,
                              float* __restrict__ core) {
  __shared__ float s_w[64][4];
  __shared__ int   s_t[64][4];

  const int n   = blockIdx.x;
  const int lq0 = blockIdx.y * 4;
  const int z   = blockIdx.z;
  const int tid = threadIdx.x;

  if (tid < 64) {
    const int i = tid >> 4;          // lq within group
    const int m = (tid >> 2) & 3;    // head
    const int p = tid & 3;           // point
    const int lq = lq0 + i;
    const float* row = OA + ((size_t)n * LQ + lq) * 64;

    const float l0 = row[32 + m * 4 + 0];
    const float l1 = row[32 + m * 4 + 1];
    const float l2 = row[32 + m * 4 + 2];
    const float l3 = row[32 + m * 4 + 3];
    const float mx = fmaxf(fmaxf(l0, l1), fmaxf(l2, l3));
    const float e0 = __expf(l0 - mx), e1 = __expf(l1 - mx);
    const float e2 = __expf(l2 - mx), e3 = __expf(l3 - mx);
    const float inv = 1.f / (e0 + e1 + e2 + e3);
    const float ep[4] = {e0, e1, e2, e3};
    const float ew = ep[p] * inv;

    const int h = lq / 14, w = lq - (lq / 14) * 14;
    const float px = (float)w * (14.f / 13.f) - 0.5f + row[(m * 4 + p) * 2 + 0];
    const float py = (float)h * (14.f / 13.f) - 0.5f + row[(m * 4 + p) * 2 + 1];
    const float fx = floorf(px), fy = floorf(py);
    const int x0 = (int)fx, y0 = (int)fy;
    const float wx1 = px - fx, wy1 = py - fy;
    const float wx0 = 1.f - wx1, wy0 = 1.f - wy1;

    const bool vx0 = (x0 >= 0) & (x0 < 14);
    const bool vx1 = (x0 >= -1) & (x0 < 13);
    const bool vy0 = (y0 >= 0) & (y0 < 14);
    const bool vy1 = (y0 >= -1) & (y0 < 13);
    const int cx0 = min(max(x0, 0), 13),      cx1 = min(max(x0 + 1, 0), 13);
    const int cy0 = min(max(y0, 0), 13) * 14, cy1 = min(max(y0 + 1, 0), 13) * 14;

    s_w[tid][0] = (vx0 & vy0) ? ew * wx0 * wy0 : 0.f;
    s_w[tid][1] = (vx1 & vy0) ? ew * wx1 * wy0 : 0.f;
    s_w[tid][2] = (vx0 & vy1) ? ew * wx0 * wy1 : 0.f;
    s_w[tid][3] = (vx1 & vy1) ? ew * wx1 * wy1 : 0.f;
    s_t[tid][0] = cy0 + cx0;
    s_t[tid][1] = cy0 + cx1;
    s_t[tid][2] = cy1 + cx0;
    s_t[tid][3] = cy1 + cx1;
  }
  __syncthreads();

  const int ch = z * 256 + tid;     // 0..767 (value column)
  const int m  = ch / DH;           // head (wave-uniform)
  const bf16* vb = Vb + (size_t)n * LQ * 768 + ch;
  float acc = 0.f;
#pragma unroll
  for (int i = 0; i < 4; ++i) {
#pragma unroll
    for (int p = 0; p < 4; ++p) {
      const int e = i * 16 + m * 4 + p;
      const float4 w4 = *(const float4*)s_w[e];
      const int4   t4 = *(const int4*)s_t[e];
      acc += w4.x * (float)vb[(size_t)t4.x * 768];
      acc += w4.y * (float)vb[(size_t)t4.y * 768];
      acc += w4.z * (float)vb[(size_t)t4.z * 768];
      acc += w4.w * (float)vb[(size_t)t4.w * 768];
    }
  }
  atomicAdd(&core[(size_t)n * DM + ch], acc * (1.f / 196.f));
}

// ---------------------------------------------------------------------------
// small_linear: out[n][d] = sum_k in[n][k] * W[d][k] + b[d]
// ---------------------------------------------------------------------------
__global__ void small_linear(const float* __restrict__ in,
                             const float* __restrict__ W,
                             const float* __restrict__ b,
                             float* __restrict__ out) {
  const int n = blockIdx.x;
  const int d = blockIdx.y * 256 + threadIdx.x;
  const float4* a4 = (const float4*)(in + (size_t)n * DM);
  const float4* w4 = (const float4*)(W + (size_t)d * DM);
  float acc = 0.f;
#pragma unroll 4
  for (int k = 0; k < DM / 4; ++k) {
    float4 a = a4[k], w = w4[k];
    acc += a.x * w.x + a.y * w.y + a.z * w.z + a.w * w.w;
  }
  out[(size_t)n * DM + d] = acc + b[d];
}

// ---------------------------------------------------------------------------
extern "C" void kernel_launch(void* const* d_in, const int* in_sizes, int n_in,
                              void* d_out, int out_size, void* d_ws, size_t ws_size,
                              hipStream_t stream) {
  const float* x       = (const float*)d_in[0];
  const float* embed_w = (const float*)d_in[1];
  const float* embed_b = (const float*)d_in[2];
  const float* value_w = (const float*)d_in[3];
  const float* value_b = (const float*)d_in[4];
  const float* off_w   = (const float*)d_in[5];
  const float* off_b   = (const float*)d_in[6];
  const float* aw_w    = (const float*)d_in[7];
  const float* aw_b    = (const float*)d_in[8];
  const float* outp_w  = (const float*)d_in[9];
  const float* outp_b  = (const float*)d_in[10];
  const float* proj_w  = (const float*)d_in[11];
  const float* proj_b  = (const float*)d_in[12];
  float* out = (float*)d_out;

  char* ws = (char*)d_ws;
  bf16*  A      = (bf16*)(ws + OFF_A);
  bf16*  WembT  = (bf16*)(ws + OFF_WEMBT);
  bf16*  Wcat   = (bf16*)(ws + OFF_WCAT);
  bf16*  Wfused = (bf16*)(ws + OFF_WFUSE);
  float* bfused = (float*)(ws + OFF_BFUSE);
  float* zb     = (float*)(ws + OFF_ZB);
  bf16*  Vbuf   = (bf16*)(ws + OFF_VBUF);
  float* OA     = (float*)(ws + OFF_OA);
  float* core   = (float*)(ws + OFF_CORE);
  float* pooled = (float*)(ws + OFF_POOL);

  stage_kernel<<<dim3(12124), dim3(256), 0, stream>>>(
      x, embed_w, embed_b, value_w, off_w, aw_w, value_b, off_b, aw_b,
      A, WembT, Wcat, bfused, zb, core);

  // Wfused[r][k] = sum_j Wcat[r][j] * WembT[k][j] = (Wcat@Wemb)[r][k]
  gemm_bt<bf16><<<dim3(DM / 128, NCAT / 128), dim3(256), 0, stream>>>(
      Wcat, WembT, zb, Wfused, NCAT, DM, DM);

  gemm2_mixed<<<dim3(NCAT / 128, M_ROWS / 128), dim3(256), 0, stream>>>(
      A, Wfused, bfused, Vbuf, OA, M_ROWS, NCAT, DM);

  deform_kernel<<<dim3(N_IMG, 49, 3), dim3(256), 0, stream>>>(Vbuf, OA, core);

  small_linear<<<dim3(N_IMG, 3), dim3(256), 0, stream>>>(core, outp_w, outp_b, pooled);
  small_linear<<<dim3(N_IMG, 3), dim3(256), 0, stream>>>(pooled, proj_w, proj_b, out);
}